// Round 1
// baseline (384.193 us; speedup 1.0000x reference)
//
#include <hip/hip_runtime.h>
#include <math.h>

#define PS 16
#define PH 64
#define PWD 64
#define NB 32
#define IW 1024
#define IH 1024
#define NPATCH (PH*PWD)

__device__ __forceinline__ float clamp01(float v) {
    return fminf(fmaxf(v, 0.0f), 1.0f);
}

// One block per (b, ph) strip: 16 rows x 1024 cols. 256 threads, float4 each.
__global__ __launch_bounds__(256) void stats_kernel(const float* __restrict__ img,
                                                    float* __restrict__ ws_mean,
                                                    float* __restrict__ ws_qual) {
    const int blk = blockIdx.x;            // b*64 + ph
    const int b  = blk >> 6;
    const int ph = blk & 63;
    const int t  = threadIdx.x;

    size_t base = ((size_t)b * IH + (size_t)ph * PS) * IW + (size_t)t * 4;
    float s = 0.0f, ss = 0.0f;
#pragma unroll
    for (int i = 0; i < PS; ++i) {
        float4 v = *(const float4*)(img + base + (size_t)i * IW);
        s  += v.x + v.y + v.z + v.w;
        ss += v.x * v.x + v.y * v.y + v.z * v.z + v.w * v.w;
    }
    // 4 threads per patch-column: reduce within the 4-lane group
    s  += __shfl_xor(s, 1);  ss += __shfl_xor(ss, 1);
    s  += __shfl_xor(s, 2);  ss += __shfl_xor(ss, 2);

    if ((t & 3) == 0) {
        float mean = s * (1.0f / 256.0f);
        float var  = (ss - s * s * (1.0f / 256.0f)) * (1.0f / 255.0f); // ddof=1
        var = fmaxf(var, 0.0f);
        float sd   = sqrtf(var);
        float iq   = 1.0f - 2.0f * fabsf(mean - 0.5f);
        float qual = (sd + iq + var) * (1.0f / 3.0f);
        int p = ph * PWD + (t >> 2);
        ws_mean[b * NPATCH + p] = mean;
        ws_qual[b * NPATCH + p] = qual;
    }
}

// One thread per patch: batch-reduce, then decide op + affine params.
// op: 0=copy, 1=noise(scale a), 2=blur, 3=affine clamp(x*a+b), 4=zero
__global__ __launch_bounds__(256) void decide_kernel(const float* __restrict__ ws_mean,
                                                     const float* __restrict__ ws_qual,
                                                     const float* __restrict__ r_strong,
                                                     const float* __restrict__ r_drop,
                                                     const float* __restrict__ r_else,
                                                     const float* __restrict__ bright_f,
                                                     const float* __restrict__ contrast_f,
                                                     const float* __restrict__ slight_f,
                                                     const int* __restrict__ aug_choice,
                                                     const int* __restrict__ slight_choice,
                                                     int* __restrict__ ws_op,
                                                     float* __restrict__ ws_a,
                                                     float* __restrict__ ws_b) {
    int p = blockIdx.x * 256 + threadIdx.x;
    if (p >= NPATCH) return;
    float qs = 0.0f, ms = 0.0f;
    for (int b = 0; b < NB; ++b) {
        qs += ws_qual[b * NPATCH + p];
        ms += ws_mean[b * NPATCH + p];
    }
    float q   = qs * (1.0f / (float)NB);
    float mpp = ms * (1.0f / (float)NB);

    bool low    = q < 0.7f;
    bool strong = low && (r_strong[p] < 0.8f);
    bool drop   = low && (q < 0.3f) && (r_drop[p] < 0.1f);
    bool els    = (!low) && (r_else[p] < 0.3f);

    int code = strong ? (aug_choice[p] + 1) : 0;
    if (els)  code = slight_choice[p] + 5;
    if (drop) code = 7;

    int op = 0; float a = 0.0f, bb = 0.0f;
    switch (code) {
        case 1: op = 1; a = 0.1f;  break;                    // noise
        case 5: op = 1; a = 0.05f; break;                    // slight noise
        case 2: op = 2; break;                               // blur
        case 3: op = 3; a = bright_f[p]; bb = 0.0f; break;   // brightness
        case 6: op = 3; a = slight_f[p]; bb = 0.0f; break;   // slight brightness
        case 4: { op = 3; float cf = contrast_f[p];          // contrast
                  a = cf; bb = mpp - mpp * cf; break; }
        case 7: op = 4; break;                               // drop
        default: break;
    }
    ws_op[p] = op; ws_a[p] = a; ws_b[p] = bb;
}

// One block per (b, ph) strip. Stage 16x1024 floats to LDS, apply per-patch op.
__global__ __launch_bounds__(256) void apply_kernel(const float* __restrict__ img,
                                                    const float* __restrict__ noise,
                                                    const int* __restrict__ ws_op,
                                                    const float* __restrict__ ws_a,
                                                    const float* __restrict__ ws_b,
                                                    float* __restrict__ out) {
    __shared__ float strip[PS][IW];   // 64 KiB
    const int blk = blockIdx.x;
    const int b  = blk >> 6;
    const int ph = blk & 63;
    const int t  = threadIdx.x;

    size_t base = ((size_t)b * IH + (size_t)ph * PS) * IW + (size_t)t * 4;
    float4* sv = (float4*)&strip[0][0];
#pragma unroll
    for (int i = 0; i < PS; ++i) {
        sv[i * 256 + t] = *(const float4*)(img + base + (size_t)i * IW);
    }
    __syncthreads();

    const int pp = ph * PWD + (t >> 2);
    const int op = ws_op[pp];
    const float a  = ws_a[pp];
    const float bb = ws_b[pp];
    const int w0 = t * 4;

    for (int i = 0; i < PS; ++i) {
        float4 x = sv[i * 256 + t];
        float4 y;
        if (op == 0) {
            y = x;
        } else if (op == 3) {               // affine: bright / contrast / slight-bright
            y.x = clamp01(fmaf(x.x, a, bb));
            y.y = clamp01(fmaf(x.y, a, bb));
            y.z = clamp01(fmaf(x.z, a, bb));
            y.w = clamp01(fmaf(x.w, a, bb));
        } else if (op == 1) {               // additive noise
            float4 n = *(const float4*)(noise + base + (size_t)i * IW);
            y.x = clamp01(fmaf(n.x, a, x.x));
            y.y = clamp01(fmaf(n.y, a, x.y));
            y.z = clamp01(fmaf(n.z, a, x.z));
            y.w = clamp01(fmaf(n.w, a, x.w));
        } else if (op == 4) {               // drop
            y.x = y.y = y.z = y.w = 0.0f;
        } else {                            // blur: patch-confined 3x3 avg, zero pad
            float vs[6];
#pragma unroll
            for (int c = 0; c < 6; ++c) {
                int col = w0 - 1 + c;
                bool valid = true;
                if (c == 0) valid = (t & 3) != 0;   // left of patch edge
                if (c == 5) valid = (t & 3) != 3;   // right of patch edge
                float sc = 0.0f;
                if (valid) {
                    if (i > 0)      sc += strip[i - 1][col];
                    sc += strip[i][col];
                    if (i < PS - 1) sc += strip[i + 1][col];
                }
                vs[c] = sc;
            }
            y.x = (vs[0] + vs[1] + vs[2]) / 9.0f;
            y.y = (vs[1] + vs[2] + vs[3]) / 9.0f;
            y.z = (vs[2] + vs[3] + vs[4]) / 9.0f;
            y.w = (vs[3] + vs[4] + vs[5]) / 9.0f;
        }
        *(float4*)(out + base + (size_t)i * IW) = y;
    }
}

extern "C" void kernel_launch(void* const* d_in, const int* in_sizes, int n_in,
                              void* d_out, int out_size, void* d_ws, size_t ws_size,
                              hipStream_t stream) {
    const float* img        = (const float*)d_in[0];
    const float* noise      = (const float*)d_in[1];
    const float* r_strong   = (const float*)d_in[2];
    const float* r_drop     = (const float*)d_in[3];
    const float* r_else     = (const float*)d_in[4];
    const float* bright_f   = (const float*)d_in[5];
    const float* contrast_f = (const float*)d_in[6];
    const float* slight_f   = (const float*)d_in[7];
    const int*   aug_choice    = (const int*)d_in[8];
    const int*   slight_choice = (const int*)d_in[9];
    float* out = (float*)d_out;

    float* ws      = (float*)d_ws;
    float* ws_mean = ws;                       // 32*4096 floats = 512 KB
    float* ws_qual = ws + NB * NPATCH;         // 512 KB
    int*   ws_op   = (int*)(ws + 2 * NB * NPATCH);  // 16 KB
    float* ws_a    = ws + 2 * NB * NPATCH + NPATCH; // 16 KB
    float* ws_b    = ws + 2 * NB * NPATCH + 2 * NPATCH;

    stats_kernel<<<NB * PH, 256, 0, stream>>>(img, ws_mean, ws_qual);
    decide_kernel<<<NPATCH / 256, 256, 0, stream>>>(ws_mean, ws_qual,
        r_strong, r_drop, r_else, bright_f, contrast_f, slight_f,
        aug_choice, slight_choice, ws_op, ws_a, ws_b);
    apply_kernel<<<NB * PH, 256, 0, stream>>>(img, noise, ws_op, ws_a, ws_b, out);
}

// Round 2
// 375.350 us; speedup vs baseline: 1.0236x; 1.0236x over previous
//
#include <hip/hip_runtime.h>
#include <math.h>

#define PS 16
#define PH 64
#define PWD 64
#define NB 32
#define IW 1024
#define IH 1024
#define NPATCH (PH*PWD)

__device__ __forceinline__ float clamp01(float v) {
    return fminf(fmaxf(v, 0.0f), 1.0f);
}

// One block per (b, ph) strip: 16 rows x 1024 cols. 256 threads, float4 each.
__global__ __launch_bounds__(256) void stats_kernel(const float* __restrict__ img,
                                                    float* __restrict__ ws_mean,
                                                    float* __restrict__ ws_qual) {
    const int blk = blockIdx.x;            // b*64 + ph
    const int b  = blk >> 6;
    const int ph = blk & 63;
    const int t  = threadIdx.x;

    size_t base = ((size_t)b * IH + (size_t)ph * PS) * IW + (size_t)t * 4;
    float s = 0.0f, ss = 0.0f;
#pragma unroll
    for (int i = 0; i < PS; ++i) {
        float4 v = *(const float4*)(img + base + (size_t)i * IW);
        s  += v.x + v.y + v.z + v.w;
        ss += v.x * v.x + v.y * v.y + v.z * v.z + v.w * v.w;
    }
    // 4 threads per patch: reduce within the 4-lane group
    s  += __shfl_xor(s, 1);  ss += __shfl_xor(ss, 1);
    s  += __shfl_xor(s, 2);  ss += __shfl_xor(ss, 2);

    if ((t & 3) == 0) {
        float mean = s * (1.0f / 256.0f);
        float var  = (ss - s * s * (1.0f / 256.0f)) * (1.0f / 255.0f); // ddof=1
        var = fmaxf(var, 0.0f);
        float sd   = sqrtf(var);
        float iq   = 1.0f - 2.0f * fabsf(mean - 0.5f);
        float qual = (sd + iq + var) * (1.0f / 3.0f);
        int p = ph * PWD + (t >> 2);
        ws_mean[b * NPATCH + p] = mean;
        ws_qual[b * NPATCH + p] = qual;
    }
}

// One thread per patch: batch-reduce, then decide op + affine params.
// op: 0=copy, 1=noise(scale a), 2=blur, 3=affine clamp(x*a+b), 4=zero
__global__ __launch_bounds__(256) void decide_kernel(const float* __restrict__ ws_mean,
                                                     const float* __restrict__ ws_qual,
                                                     const float* __restrict__ r_strong,
                                                     const float* __restrict__ r_drop,
                                                     const float* __restrict__ r_else,
                                                     const float* __restrict__ bright_f,
                                                     const float* __restrict__ contrast_f,
                                                     const float* __restrict__ slight_f,
                                                     const int* __restrict__ aug_choice,
                                                     const int* __restrict__ slight_choice,
                                                     int* __restrict__ ws_op,
                                                     float* __restrict__ ws_a,
                                                     float* __restrict__ ws_b) {
    int p = blockIdx.x * 256 + threadIdx.x;
    if (p >= NPATCH) return;
    float qs = 0.0f, ms = 0.0f;
    for (int b = 0; b < NB; ++b) {
        qs += ws_qual[b * NPATCH + p];
        ms += ws_mean[b * NPATCH + p];
    }
    float q   = qs * (1.0f / (float)NB);
    float mpp = ms * (1.0f / (float)NB);

    bool low    = q < 0.7f;
    bool strong = low && (r_strong[p] < 0.8f);
    bool drop   = low && (q < 0.3f) && (r_drop[p] < 0.1f);
    bool els    = (!low) && (r_else[p] < 0.3f);

    int code = strong ? (aug_choice[p] + 1) : 0;
    if (els)  code = slight_choice[p] + 5;
    if (drop) code = 7;

    int op = 0; float a = 0.0f, bb = 0.0f;
    switch (code) {
        case 1: op = 1; a = 0.1f;  break;                    // noise
        case 5: op = 1; a = 0.05f; break;                    // slight noise
        case 2: op = 2; break;                               // blur
        case 3: op = 3; a = bright_f[p]; bb = 0.0f; break;   // brightness
        case 6: op = 3; a = slight_f[p]; bb = 0.0f; break;   // slight brightness
        case 4: { op = 3; float cf = contrast_f[p];          // contrast
                  a = cf; bb = mpp - mpp * cf; break; }
        case 7: op = 4; break;                               // drop
        default: break;
    }
    ws_op[p] = op; ws_a[p] = a; ws_b[p] = bb;
}

// One block per (b, ph) strip, NO LDS. 4 lanes per 16-wide patch (float4/lane).
// Simple ops: single masked pass. Blur: second masked pass with a rolling
// 3-row register window; horizontal neighbors via intra-patch-group shfl.
__global__ __launch_bounds__(256) void apply_kernel(const float* __restrict__ img,
                                                    const float* __restrict__ noise,
                                                    const int* __restrict__ ws_op,
                                                    const float* __restrict__ ws_a,
                                                    const float* __restrict__ ws_b,
                                                    float* __restrict__ out) {
    const int blk = blockIdx.x;
    const int b  = blk >> 6;
    const int ph = blk & 63;
    const int t  = threadIdx.x;

    const size_t base = ((size_t)b * IH + (size_t)ph * PS) * IW + (size_t)t * 4;

    const int pp = ph * PWD + (t >> 2);
    const int op = ws_op[pp];
    const float a  = ws_a[pp];
    const float bb = ws_b[pp];

    if (op != 2) {   // copy / noise / affine / zero — streaming pass
#pragma unroll 4
        for (int i = 0; i < PS; ++i) {
            float4 x = *(const float4*)(img + base + (size_t)i * IW);
            float4 y;
            if (op == 1) {                  // additive noise
                float4 n = *(const float4*)(noise + base + (size_t)i * IW);
                y.x = clamp01(fmaf(n.x, a, x.x));
                y.y = clamp01(fmaf(n.y, a, x.y));
                y.z = clamp01(fmaf(n.z, a, x.z));
                y.w = clamp01(fmaf(n.w, a, x.w));
            } else if (op == 3) {           // affine: bright / contrast / slight-bright
                y.x = clamp01(fmaf(x.x, a, bb));
                y.y = clamp01(fmaf(x.y, a, bb));
                y.z = clamp01(fmaf(x.z, a, bb));
                y.w = clamp01(fmaf(x.w, a, bb));
            } else if (op == 4) {           // drop
                y.x = y.y = y.z = y.w = 0.0f;
            } else {
                y = x;
            }
            *(float4*)(out + base + (size_t)i * IW) = y;
        }
    }
    if (op == 2) {   // patch-confined 3x3 box blur, zero padding at patch edges
        const bool left_edge  = (t & 3) == 0;
        const bool right_edge = (t & 3) == 3;
        float4 prev = make_float4(0.f, 0.f, 0.f, 0.f);
        float4 cur  = *(const float4*)(img + base);
        float4 next;
        for (int i = 0; i < PS; ++i) {
            if (i < PS - 1) next = *(const float4*)(img + base + (size_t)(i + 1) * IW);
            else            next = make_float4(0.f, 0.f, 0.f, 0.f);
            float4 v;
            v.x = prev.x + cur.x + next.x;
            v.y = prev.y + cur.y + next.y;
            v.z = prev.z + cur.z + next.z;
            v.w = prev.w + cur.w + next.w;
            // neighbor columns across lanes (same patch group => lanes active)
            float left  = __shfl_up(v.w, 1);
            float right = __shfl_down(v.x, 1);
            if (left_edge)  left  = 0.0f;
            if (right_edge) right = 0.0f;
            float4 y;
            y.x = (left + v.x + v.y) * (1.0f / 9.0f);
            y.y = (v.x + v.y + v.z) * (1.0f / 9.0f);
            y.z = (v.y + v.z + v.w) * (1.0f / 9.0f);
            y.w = (v.z + v.w + right) * (1.0f / 9.0f);
            *(float4*)(out + base + (size_t)i * IW) = y;
            prev = cur; cur = next;
        }
    }
}

extern "C" void kernel_launch(void* const* d_in, const int* in_sizes, int n_in,
                              void* d_out, int out_size, void* d_ws, size_t ws_size,
                              hipStream_t stream) {
    const float* img        = (const float*)d_in[0];
    const float* noise      = (const float*)d_in[1];
    const float* r_strong   = (const float*)d_in[2];
    const float* r_drop     = (const float*)d_in[3];
    const float* r_else     = (const float*)d_in[4];
    const float* bright_f   = (const float*)d_in[5];
    const float* contrast_f = (const float*)d_in[6];
    const float* slight_f   = (const float*)d_in[7];
    const int*   aug_choice    = (const int*)d_in[8];
    const int*   slight_choice = (const int*)d_in[9];
    float* out = (float*)d_out;

    float* ws      = (float*)d_ws;
    float* ws_mean = ws;                       // 32*4096 floats = 512 KB
    float* ws_qual = ws + NB * NPATCH;         // 512 KB
    int*   ws_op   = (int*)(ws + 2 * NB * NPATCH);  // 16 KB
    float* ws_a    = ws + 2 * NB * NPATCH + NPATCH; // 16 KB
    float* ws_b    = ws + 2 * NB * NPATCH + 2 * NPATCH;

    stats_kernel<<<NB * PH, 256, 0, stream>>>(img, ws_mean, ws_qual);
    decide_kernel<<<NPATCH / 256, 256, 0, stream>>>(ws_mean, ws_qual,
        r_strong, r_drop, r_else, bright_f, contrast_f, slight_f,
        aug_choice, slight_choice, ws_op, ws_a, ws_b);
    apply_kernel<<<NB * PH, 256, 0, stream>>>(img, noise, ws_op, ws_a, ws_b, out);
}

// Round 3
// 355.123 us; speedup vs baseline: 1.0819x; 1.0570x over previous
//
#include <hip/hip_runtime.h>
#include <math.h>

#define PS 16
#define PH 64
#define PWD 64
#define NB 32
#define IW 1024
#define IH 1024
#define NPATCH (PH*PWD)

__device__ __forceinline__ float clamp01(float v) {
    return fminf(fmaxf(v, 0.0f), 1.0f);
}

// One block per (b, ph) strip: 16 rows x 1024 cols. 256 threads, float4 each.
__global__ __launch_bounds__(256) void stats_kernel(const float* __restrict__ img,
                                                    float* __restrict__ ws_mean,
                                                    float* __restrict__ ws_qual) {
    const int blk = blockIdx.x;            // b*64 + ph
    const int b  = blk >> 6;
    const int ph = blk & 63;
    const int t  = threadIdx.x;

    size_t base = ((size_t)b * IH + (size_t)ph * PS) * IW + (size_t)t * 4;
    float s = 0.0f, ss = 0.0f;
#pragma unroll
    for (int i = 0; i < PS; ++i) {
        float4 v = *(const float4*)(img + base + (size_t)i * IW);
        s  += v.x + v.y + v.z + v.w;
        ss += v.x * v.x + v.y * v.y + v.z * v.z + v.w * v.w;
    }
    // 4 threads per patch: reduce within the 4-lane group
    s  += __shfl_xor(s, 1);  ss += __shfl_xor(ss, 1);
    s  += __shfl_xor(s, 2);  ss += __shfl_xor(ss, 2);

    if ((t & 3) == 0) {
        float mean = s * (1.0f / 256.0f);
        float var  = (ss - s * s * (1.0f / 256.0f)) * (1.0f / 255.0f); // ddof=1
        var = fmaxf(var, 0.0f);
        float sd   = sqrtf(var);
        float iq   = 1.0f - 2.0f * fabsf(mean - 0.5f);
        float qual = (sd + iq + var) * (1.0f / 3.0f);
        int p = ph * PWD + (t >> 2);
        ws_mean[b * NPATCH + p] = mean;
        ws_qual[b * NPATCH + p] = qual;
    }
}

// One block per (b, ph) strip. Fused decide (threads 0..63 -> LDS param table)
// + uniform apply pass with rolling 3-row window (no divergent re-loads).
__global__ __launch_bounds__(256) void apply_kernel(const float* __restrict__ img,
                                                    const float* __restrict__ noise,
                                                    const float* __restrict__ ws_mean,
                                                    const float* __restrict__ ws_qual,
                                                    const float* __restrict__ r_strong,
                                                    const float* __restrict__ r_drop,
                                                    const float* __restrict__ r_else,
                                                    const float* __restrict__ bright_f,
                                                    const float* __restrict__ contrast_f,
                                                    const float* __restrict__ slight_f,
                                                    const int* __restrict__ aug_choice,
                                                    const int* __restrict__ slight_choice,
                                                    float* __restrict__ out) {
    __shared__ int   s_op[PWD];
    __shared__ float s_a[PWD];
    __shared__ float s_b[PWD];

    const int blk = blockIdx.x;
    const int b  = blk >> 6;
    const int ph = blk & 63;
    const int t  = threadIdx.x;

    // ---- fused decide: one thread per patch in this strip ----
    if (t < PWD) {
        const int p = ph * PWD + t;
        float qs = 0.0f, ms = 0.0f;
#pragma unroll 8
        for (int bi = 0; bi < NB; ++bi) {
            qs += ws_qual[bi * NPATCH + p];
            ms += ws_mean[bi * NPATCH + p];
        }
        float q   = qs * (1.0f / (float)NB);
        float mpp = ms * (1.0f / (float)NB);

        bool low    = q < 0.7f;
        bool strong = low && (r_strong[p] < 0.8f);
        bool drop   = low && (q < 0.3f) && (r_drop[p] < 0.1f);
        bool els    = (!low) && (r_else[p] < 0.3f);

        int code = strong ? (aug_choice[p] + 1) : 0;
        if (els)  code = slight_choice[p] + 5;
        if (drop) code = 7;

        int op = 0; float a = 0.0f, bb = 0.0f;
        switch (code) {
            case 1: op = 1; a = 0.1f;  break;                  // noise
            case 5: op = 1; a = 0.05f; break;                  // slight noise
            case 2: op = 2; break;                             // blur
            case 3: op = 3; a = bright_f[p]; break;            // brightness
            case 6: op = 3; a = slight_f[p]; break;            // slight brightness
            case 4: { op = 3; float cf = contrast_f[p];        // contrast
                      a = cf; bb = mpp - mpp * cf; break; }
            case 7: op = 4; break;                             // drop
            default: break;
        }
        s_op[t] = op; s_a[t] = a; s_b[t] = bb;
    }
    __syncthreads();

    const int pw = t >> 2;
    const int op   = s_op[pw];
    const float a  = s_a[pw];
    const float bb = s_b[pw];
    const bool left_edge  = (t & 3) == 0;
    const bool right_edge = (t & 3) == 3;

    const size_t base = ((size_t)b * IH + (size_t)ph * PS) * IW + (size_t)t * 4;

    // ---- uniform pass: rolling 3-row window, each row loaded once ----
    float4 prev = make_float4(0.f, 0.f, 0.f, 0.f);
    float4 cur  = *(const float4*)(img + base);
    float4 next;
#pragma unroll 4
    for (int i = 0; i < PS; ++i) {
        if (i < PS - 1) next = *(const float4*)(img + base + (size_t)(i + 1) * IW);
        else            next = make_float4(0.f, 0.f, 0.f, 0.f);

        float4 y;
        if (op == 2) {               // patch-confined 3x3 box blur, zero pad
            float4 v;
            v.x = prev.x + cur.x + next.x;
            v.y = prev.y + cur.y + next.y;
            v.z = prev.z + cur.z + next.z;
            v.w = prev.w + cur.w + next.w;
            float left  = __shfl_up(v.w, 1);
            float right = __shfl_down(v.x, 1);
            if (left_edge)  left  = 0.0f;
            if (right_edge) right = 0.0f;
            y.x = (left + v.x + v.y) * (1.0f / 9.0f);
            y.y = (v.x + v.y + v.z) * (1.0f / 9.0f);
            y.z = (v.y + v.z + v.w) * (1.0f / 9.0f);
            y.w = (v.z + v.w + right) * (1.0f / 9.0f);
        } else if (op == 1) {        // additive noise
            float4 n = *(const float4*)(noise + base + (size_t)i * IW);
            y.x = clamp01(fmaf(n.x, a, cur.x));
            y.y = clamp01(fmaf(n.y, a, cur.y));
            y.z = clamp01(fmaf(n.z, a, cur.z));
            y.w = clamp01(fmaf(n.w, a, cur.w));
        } else if (op == 3) {        // affine: bright / contrast / slight-bright
            y.x = clamp01(fmaf(cur.x, a, bb));
            y.y = clamp01(fmaf(cur.y, a, bb));
            y.z = clamp01(fmaf(cur.z, a, bb));
            y.w = clamp01(fmaf(cur.w, a, bb));
        } else if (op == 4) {        // drop
            y.x = y.y = y.z = y.w = 0.0f;
        } else {                     // identity
            y = cur;
        }
        *(float4*)(out + base + (size_t)i * IW) = y;
        prev = cur; cur = next;
    }
}

extern "C" void kernel_launch(void* const* d_in, const int* in_sizes, int n_in,
                              void* d_out, int out_size, void* d_ws, size_t ws_size,
                              hipStream_t stream) {
    const float* img        = (const float*)d_in[0];
    const float* noise      = (const float*)d_in[1];
    const float* r_strong   = (const float*)d_in[2];
    const float* r_drop     = (const float*)d_in[3];
    const float* r_else     = (const float*)d_in[4];
    const float* bright_f   = (const float*)d_in[5];
    const float* contrast_f = (const float*)d_in[6];
    const float* slight_f   = (const float*)d_in[7];
    const int*   aug_choice    = (const int*)d_in[8];
    const int*   slight_choice = (const int*)d_in[9];
    float* out = (float*)d_out;

    float* ws      = (float*)d_ws;
    float* ws_mean = ws;                       // 32*4096 floats = 512 KB
    float* ws_qual = ws + NB * NPATCH;         // 512 KB

    stats_kernel<<<NB * PH, 256, 0, stream>>>(img, ws_mean, ws_qual);
    apply_kernel<<<NB * PH, 256, 0, stream>>>(img, noise, ws_mean, ws_qual,
        r_strong, r_drop, r_else, bright_f, contrast_f, slight_f,
        aug_choice, slight_choice, out);
}